// Round 3
// baseline (208.579 us; speedup 1.0000x reference)
//
#include <hip/hip_runtime.h>
#include <math.h>

#define B_ 8
#define N_ 1024
#define D_ 512
#define H_ 4
#define ND (N_ * D_)      // 524288
#define DD (D_ * D_)      // 262144
#define NN (N_ * N_)      // 1048576

typedef _Float16 f16;
typedef f16 f16x8 __attribute__((ext_vector_type(8)));
typedef float f32x4 __attribute__((ext_vector_type(4)));

typedef __attribute__((address_space(3))) void lds_void;
typedef __attribute__((address_space(1))) void g_void;

// =====================================================================
// 256x256 8-phase GEMM core (T2 swizzle + T3 8-phase + T4 counted vmcnt
// + T5 setprio), plain-HIP port of the m201 template.
// C[M,N] = scale * A[M,K] @ B[N,K]^T, all f16, K-major operands.
// 512 threads = 8 waves (2 row-groups x 4 col-groups, interleaved so
// quadrant qr reads exactly A-half qr, quadrant qc exactly B-half qc).
// LDS: 2 x (A 256x64 + B 256x64) f16 = 128 KiB, double buffered.
// Stage schedule per tile t: p0->(t+1)A1, p1->(t+1)B1, p2->(t+2)A0,
// p3->(t+2)B0; each target region died one phase earlier. End-of-tile
// s_waitcnt vmcnt(4) (2 half-tiles in flight); vmcnt(0) only at tail.
// T2: LDS chunk swizzle c^=(row&7) applied on the READ side; write side
// achieved by pre-swizzling the global SOURCE chunk ((l&7)^(l>>3)) with
// a linear global_load_lds destination (rule #21 / m173).
// =====================================================================

#define PHASE_(PA, PB, QR, QC, STAGE, TAIL)                                   \
    {                                                                         \
        f16x8 av[4][2], bv[2][2];                                             \
        _Pragma("unroll")                                                     \
        for (int i_ = 0; i_ < 4; ++i_) {                                      \
            const int ra_ = (QR) * 128 + wr * 64 + i_ * 16 + fr;              \
            av[i_][0] = *(const f16x8*)(PA + ra_ * 64 + sw0 * 8);             \
            av[i_][1] = *(const f16x8*)(PA + ra_ * 64 + sw1 * 8);             \
        }                                                                     \
        _Pragma("unroll")                                                     \
        for (int j_ = 0; j_ < 2; ++j_) {                                      \
            const int rb_ = (QC) * 128 + wc * 32 + j_ * 16 + fr;              \
            bv[j_][0] = *(const f16x8*)(PB + rb_ * 64 + sw0 * 8);             \
            bv[j_][1] = *(const f16x8*)(PB + rb_ * 64 + sw1 * 8);             \
        }                                                                     \
        __builtin_amdgcn_sched_barrier(0);                                    \
        STAGE;                                                                \
        __builtin_amdgcn_s_barrier();                                         \
        asm volatile("s_waitcnt lgkmcnt(0)" ::: "memory");                    \
        __builtin_amdgcn_sched_barrier(0);                                    \
        __builtin_amdgcn_s_setprio(1);                                        \
        _Pragma("unroll")                                                     \
        for (int i_ = 0; i_ < 4; ++i_)                                        \
            _Pragma("unroll")                                                 \
            for (int j_ = 0; j_ < 2; ++j_) {                                  \
                acc[(QR)*4+i_][(QC)*2+j_] = __builtin_amdgcn_mfma_f32_16x16x32_f16(av[i_][0], bv[j_][0], acc[(QR)*4+i_][(QC)*2+j_], 0, 0, 0); \
                acc[(QR)*4+i_][(QC)*2+j_] = __builtin_amdgcn_mfma_f32_16x16x32_f16(av[i_][1], bv[j_][1], acc[(QR)*4+i_][(QC)*2+j_], 0, 0, 0); \
            }                                                                 \
        __builtin_amdgcn_s_setprio(0);                                        \
        TAIL;                                                                 \
        __builtin_amdgcn_s_barrier();                                         \
    }

template<int LDA, int LDB, int LDC, int KTOT>
__device__ __forceinline__ void gemm256(
    const f16* __restrict__ A, const f16* __restrict__ B,
    f16* __restrict__ C, float scale, int m0, int n0)
{
    constexpr int NT = KTOT / 64;
    __shared__ f16 sA0[256 * 64];
    __shared__ f16 sB0[256 * 64];
    __shared__ f16 sA1[256 * 64];
    __shared__ f16 sB1[256 * 64];

    const int t = threadIdx.x;
    const int w = t >> 6, l = t & 63;
    const int fr = l & 15, fq = l >> 4;     // MFMA fragment row / k-chunk
    const int wr = w >> 2, wc = w & 3;      // wave row-group / col-group
    const int lr = l >> 3, lc = l & 7;      // stage window row / chunk
    const int swc = lc ^ lr;                // pre-swizzled SOURCE chunk
    const int sw0 = fq ^ (fr & 7);          // read swizzle, ks=0
    const int sw1 = (4 + fq) ^ (fr & 7);    // read swizzle, ks=1

    f32x4 acc[8][4] = {};

    auto stageA = [&](f16* buf, int half, int kt) {
#pragma unroll
        for (int i = 0; i < 2; ++i) {
            const int r0 = half * 128 + i * 64 + w * 8;
            const f16* g = A + (size_t)(m0 + r0 + lr) * LDA + kt * 64 + swc * 8;
            __builtin_amdgcn_global_load_lds((g_void*)g, (lds_void*)(buf + r0 * 64), 16, 0, 0);
        }
    };
    auto stageB = [&](f16* buf, int half, int kt) {
#pragma unroll
        for (int i = 0; i < 2; ++i) {
            const int r0 = half * 128 + i * 64 + w * 8;
            const f16* g = B + (size_t)(n0 + r0 + lr) * LDB + kt * 64 + swc * 8;
            __builtin_amdgcn_global_load_lds((g_void*)g, (lds_void*)(buf + r0 * 64), 16, 0, 0);
        }
    };

    // prologue: tile0 (4 halves) + tile1 (A0,B0) = 12 loads; drain tile0.
    stageA(sA0, 0, 0); stageB(sB0, 0, 0);
    stageA(sA0, 1, 0); stageB(sB0, 1, 0);
    if (NT > 1) { stageA(sA1, 0, 1); stageB(sB1, 0, 1); }
    asm volatile("s_waitcnt vmcnt(4)" ::: "memory");
    __builtin_amdgcn_s_barrier();

#pragma unroll 2
    for (int kt = 0; kt < NT; ++kt) {
        f16* cA = (kt & 1) ? sA1 : sA0;
        f16* cB = (kt & 1) ? sB1 : sB0;
        f16* nA = (kt & 1) ? sA0 : sA1;
        f16* nB = (kt & 1) ? sB0 : sB1;
        PHASE_(cA, cB, 0, 0, { if (kt + 1 < NT) stageA(nA, 1, kt + 1); }, {});
        PHASE_(cA, cB, 0, 1, { if (kt + 1 < NT) stageB(nB, 1, kt + 1); }, {});
        PHASE_(cA, cB, 1, 0, { if (kt + 2 < NT) stageA(cA, 0, kt + 2); }, {});
        PHASE_(cA, cB, 1, 1, { if (kt + 2 < NT) stageB(cB, 0, kt + 2); },
               { if (kt + 2 < NT) { asm volatile("s_waitcnt vmcnt(4)" ::: "memory"); }
                 else             { asm volatile("s_waitcnt vmcnt(0)" ::: "memory"); } });
    }

    // epilogue: interleaved mapping -> global C
#pragma unroll
    for (int ri = 0; ri < 8; ++ri)
#pragma unroll
        for (int cj = 0; cj < 4; ++cj)
#pragma unroll
            for (int rr = 0; rr < 4; ++rr) {
                const int row = m0 + (ri >> 2) * 128 + wr * 64 + (ri & 3) * 16 + fq * 4 + rr;
                const int col = n0 + (cj >> 1) * 128 + wc * 32 + (cj & 1) * 16 + fr;
                C[(size_t)row * LDC + col] = (f16)(acc[ri][cj][rr] * scale);
            }
}

// GEMM1: Yh[z] = f16( x[b] @ Wh[h] ), z=b*4+h. xcd=b. 256 blocks.
// M=1024,N=512,K=512 -> 8 tiles/z.
__global__ __launch_bounds__(512, 2) void k_g1(
    const f16* __restrict__ xfh, const f16* __restrict__ wTh,
    f16* __restrict__ Yh)
{
    const int i = blockIdx.x;
    const int b = i & 7;
    const int li = i >> 3;            // 0..31
    const int h = li >> 3;
    const int tile = li & 7;
    const int m0 = (tile >> 1) * 256;
    const int n0 = (tile & 1) * 256;
    const int z = b * 4 + h;
    gemm256<D_, D_, D_, D_>(
        xfh + (size_t)b * ND,
        wTh + (size_t)h * DD,
        Yh + (size_t)z * ND, 1.0f, m0, n0);
}

// GEMM2: S[z] = f16( Yh[z] @ xh[b]^T * scale ). xcd=b. 512 blocks.
// M=1024,N=1024,K=512 -> 16 tiles/z.
__global__ __launch_bounds__(512, 2) void k_g2(
    const f16* __restrict__ Yh, const f16* __restrict__ xfh,
    f16* __restrict__ S)
{
    const int i = blockIdx.x;
    const int b = i & 7;
    const int li = i >> 3;           // 0..63
    const int h = li >> 4;
    const int tile = li & 15;
    const int m0 = (tile >> 2) * 256;
    const int n0 = (tile & 3) * 256;
    const int z = b * 4 + h;
    gemm256<D_, D_, N_, D_>(
        Yh + (size_t)z * ND,
        xfh + (size_t)b * ND,
        S + (size_t)z * NN, 0.044194173824159216f, m0, n0);
}

// GEMM4 split-K by head: part[z] = f16( P[z] @ xT[b]^T ). xcd=b. 256 blocks.
// M=1024,N=512,K=1024 -> 8 tiles/z.
__global__ __launch_bounds__(512, 2) void k_g4(
    const f16* __restrict__ P, const f16* __restrict__ xT,
    f16* __restrict__ part)
{
    const int i = blockIdx.x;
    const int b = i & 7;
    const int li = i >> 3;            // 0..31
    const int h = li >> 3;
    const int tile = li & 7;
    const int m0 = (tile >> 1) * 256;
    const int n0 = (tile & 1) * 256;
    const int z = b * 4 + h;
    gemm256<N_, N_, D_, N_>(
        P + (size_t)z * NN,
        xT + (size_t)b * ND,
        part + (size_t)z * ND, 1.0f, m0, n0);
}

// Reduce: out[b] = 0.25 * sum_h part[b*4+h]   (f16 partials, 8 elems/thread)
__global__ __launch_bounds__(256) void k_reduce(
    const f16* __restrict__ part, float* __restrict__ out)
{
    const int i = blockIdx.x * 256 + threadIdx.x;
    const int b = i / (ND / 8);
    const int r = i - b * (ND / 8);
    const f16x8* p = (const f16x8*)part;
    f16x8 a0 = p[(size_t)(b * 4 + 0) * (ND / 8) + r];
    f16x8 a1 = p[(size_t)(b * 4 + 1) * (ND / 8) + r];
    f16x8 a2 = p[(size_t)(b * 4 + 2) * (ND / 8) + r];
    f16x8 a3 = p[(size_t)(b * 4 + 3) * (ND / 8) + r];
    float4 o0, o1;
    float* o = (float*)&o0;
#pragma unroll
    for (int k = 0; k < 4; ++k)
        o[k] = 0.25f * ((float)a0[k] + (float)a1[k] + (float)a2[k] + (float)a3[k]);
    o = (float*)&o1;
#pragma unroll
    for (int k = 0; k < 4; ++k)
        o[k] = 0.25f * ((float)a0[k+4] + (float)a1[k+4] + (float)a2[k+4] + (float)a3[k+4]);
    ((float4*)out)[(size_t)i * 2]     = o0;
    ((float4*)out)[(size_t)i * 2 + 1] = o1;
}

// Merged decomp: z<8 -> x-batch z (f16 hi + transposed hi); z>=8 -> W head
// z-8 (hi only + transpose). Grid (8,16,12); W part uses y<8 only.
__global__ __launch_bounds__(256) void decomp_xw(
    const float* __restrict__ x, const float* __restrict__ W,
    f16* __restrict__ xfh, f16* __restrict__ xT, f16* __restrict__ wTh)
{
    __shared__ f16 tile[64][65];
    __shared__ float tw[64][65];
    const int t = threadIdx.x;
    const int z = blockIdx.z;
    if (z < 8) {
        const int b = z, n0 = blockIdx.y * 64, d0 = blockIdx.x * 64;
        const float* xb = x + (size_t)b * ND;
#pragma unroll
        for (int p = 0; p < 16; ++p) {
            const int idx = t + p * 256;
            const int r = idx >> 6, c = idx & 63;
            const float v = xb[(size_t)(n0 + r) * D_ + d0 + c];
            const f16 h = (f16)v;
            xfh[(size_t)b * ND + (size_t)(n0 + r) * D_ + d0 + c] = h;
            tile[r][c] = h;
        }
        __syncthreads();
#pragma unroll
        for (int p = 0; p < 16; ++p) {
            const int idx = t + p * 256;
            const int r = idx >> 6, c = idx & 63;
            xT[(size_t)b * ND + (size_t)(d0 + r) * N_ + n0 + c] = tile[c][r];
        }
    } else {
        if (blockIdx.y >= 8) return;
        const int h = z - 8, d0 = blockIdx.y * 64, e0 = blockIdx.x * 64;
        const float* Wh = W + (size_t)h * DD;
#pragma unroll
        for (int p = 0; p < 16; ++p) {
            const int idx = t + p * 256;
            const int r = idx >> 6, c = idx & 63;
            tw[r][c] = Wh[(size_t)(d0 + r) * D_ + e0 + c];
        }
        __syncthreads();
#pragma unroll
        for (int p = 0; p < 16; ++p) {
            const int idx = t + p * 256;
            const int r = idx >> 6, c = idx & 63;
            wTh[(size_t)h * DD + (size_t)(e0 + r) * D_ + d0 + c] = (f16)tw[c][r];
        }
    }
}

// Barrier-free softmax, XCD-aligned: block i -> b = i&7 (same placement as
// the g2 blocks that wrote S[b's z-range]) so S reads hit the local L2.
// One wave per row, 4 rows/block. 8192 blocks.
__global__ __launch_bounds__(256) void softmax_wave(
    const f16* __restrict__ S, f16* __restrict__ P)
{
    const int wave = threadIdx.x >> 6;
    const int l = threadIdx.x & 63;
    const int i = blockIdx.x;
    const int b = i & 7;
    const int li = i >> 3;            // 0..1023
    const int h = li >> 8;            // 0..3
    const int rg = li & 255;          // 0..255 row-group (4 rows)
    const size_t row = (size_t)(b * 4 + h) * N_ + rg * 4 + wave;

    const f16x8* p = (const f16x8*)(S + row * N_);
    f16x8 v0 = p[l * 2], v1 = p[l * 2 + 1];

    float f[16];
#pragma unroll
    for (int k = 0; k < 8; ++k) { f[k] = (float)v0[k]; f[k + 8] = (float)v1[k]; }

    float m = f[0];
#pragma unroll
    for (int k = 1; k < 16; ++k) m = fmaxf(m, f[k]);
#pragma unroll
    for (int o = 32; o > 0; o >>= 1) m = fmaxf(m, __shfl_xor(m, o));

    float s = 0.f;
#pragma unroll
    for (int k = 0; k < 16; ++k) { f[k] = __expf(f[k] - m); s += f[k]; }
#pragma unroll
    for (int o = 32; o > 0; o >>= 1) s += __shfl_xor(s, o);

    const float inv = 1.0f / s;
    f16x8 o0, o1;
#pragma unroll
    for (int k = 0; k < 8; ++k) {
        o0[k] = (f16)(f[k] * inv);
        o1[k] = (f16)(f[k + 8] * inv);
    }
    f16x8* q = (f16x8*)(P + row * N_);
    q[l * 2] = o0;
    q[l * 2 + 1] = o1;
}

extern "C" void kernel_launch(void* const* d_in, const int* in_sizes, int n_in,
                              void* d_out, int out_size, void* d_ws, size_t ws_size,
                              hipStream_t stream) {
    const float* x = (const float*)d_in[0];   // [8,1024,512]
    const float* W = (const float*)d_in[1];   // [4,512,512]
    float* out = (float*)d_out;               // [8,1024,512]

    // workspace layout (proven footprint)
    char* ws = (char*)d_ws;
    const size_t MB = 1024 * 1024;
    f16*   xfh = (f16*)(ws + 0 * MB);     // 8 MiB
    f16*   xT  = (f16*)(ws + 8 * MB);     // 8 MiB
    f16*   wTh = (f16*)(ws + 16 * MB);    // 2 MiB
    f16*   Yh  = (f16*)(ws + 20 * MB);    // 32 MiB (full batch, 32 z)
    f16*   S   = (f16*)(ws + 52 * MB);    // 64 MiB (full batch, f16)
    f16*   P   = (f16*)(ws + 116 * MB);   // 64 MiB (full batch, f16)
    f16*   part = S;                      // g4 partials (32 MiB) reuse S

    decomp_xw<<<dim3(8, 16, 12), 256, 0, stream>>>(x, W, xfh, xT, wTh);

    k_g1<<<dim3(256), 512, 0, stream>>>(xfh, wTh, Yh);
    k_g2<<<dim3(512), 512, 0, stream>>>(Yh, xfh, S);
    softmax_wave<<<dim3(B_ * H_ * N_ / 4), 256, 0, stream>>>(S, P);
    k_g4<<<dim3(256), 512, 0, stream>>>(P, xT, part);
    k_reduce<<<dim3((B_ * ND / 8) / 256), 256, 0, stream>>>(part, out);
}

// Round 4
// 190.273 us; speedup vs baseline: 1.0962x; 1.0962x over previous
//
#include <hip/hip_runtime.h>
#include <math.h>

#define B_ 8
#define N_ 1024
#define D_ 512
#define H_ 4
#define ND (N_ * D_)      // 524288
#define DD (D_ * D_)      // 262144
#define NN (N_ * N_)      // 1048576

typedef _Float16 f16;
typedef f16 f16x8 __attribute__((ext_vector_type(8)));
typedef float f32x4 __attribute__((ext_vector_type(4)));

typedef __attribute__((address_space(3))) void lds_void;
typedef __attribute__((address_space(1))) void g_void;

// =====================================================================
// 256x256 8-phase GEMM core, now with CROSS-PHASE REGISTER REUSE:
// each LDS fragment is read exactly once per K-tile (24 ds_read_b128
// per wave per K-tile, the minimum; was 48). Phase plan per K-tile:
//   p0: read A0+B0 -> Q00      (stage next A-half1)
//   p1: read B1, reuse av0 -> Q01   (stage next B-half1)
//   p2: read A1, reuse bv1 -> Q11   (stage cur A-half0, t+2)
//   p3: ZERO reads, reuse av1+bv0 -> Q10  (stage cur B-half0, t+2; tail vmcnt)
// LDS-region liveness: A0,B0 dead after p0 reads; B1 after p1; A1 after
// p2 -> every stage target died >=1 phase earlier (regs carry the data).
// T2 swizzle (read-side chunk ^= row&7, write-side via pre-swizzled
// global source), T4 counted vmcnt(4) at tile end, T5 setprio. K-loop
// fully unrolled so stage conditionals fold.
// =====================================================================

#define MFMA16(QR, QC, AV, BV)                                                \
    _Pragma("unroll")                                                         \
    for (int i_ = 0; i_ < 4; ++i_)                                            \
        _Pragma("unroll")                                                     \
        for (int j_ = 0; j_ < 2; ++j_) {                                      \
            acc[(QR)*4+i_][(QC)*2+j_] = __builtin_amdgcn_mfma_f32_16x16x32_f16(AV[i_][0], BV[j_][0], acc[(QR)*4+i_][(QC)*2+j_], 0, 0, 0); \
            acc[(QR)*4+i_][(QC)*2+j_] = __builtin_amdgcn_mfma_f32_16x16x32_f16(AV[i_][1], BV[j_][1], acc[(QR)*4+i_][(QC)*2+j_], 0, 0, 0); \
        }

#define READ_A(AV, PA, HALF)                                                  \
    _Pragma("unroll")                                                         \
    for (int i_ = 0; i_ < 4; ++i_) {                                          \
        const int ra_ = (HALF) * 128 + wr * 64 + i_ * 16 + fr;                \
        AV[i_][0] = *(const f16x8*)(PA + ra_ * 64 + sw0 * 8);                 \
        AV[i_][1] = *(const f16x8*)(PA + ra_ * 64 + sw1 * 8);                 \
    }

#define READ_B(BV, PB, HALF)                                                  \
    _Pragma("unroll")                                                         \
    for (int j_ = 0; j_ < 2; ++j_) {                                          \
        const int rb_ = (HALF) * 128 + wc * 32 + j_ * 16 + fr;                \
        BV[j_][0] = *(const f16x8*)(PB + rb_ * 64 + sw0 * 8);                 \
        BV[j_][1] = *(const f16x8*)(PB + rb_ * 64 + sw1 * 8);                 \
    }

#define PHASE_SYNC_MFMA(QR, QC, AV, BV, STAGE, TAIL)                          \
    __builtin_amdgcn_sched_barrier(0);                                        \
    STAGE;                                                                    \
    __builtin_amdgcn_s_barrier();                                             \
    asm volatile("s_waitcnt lgkmcnt(0)" ::: "memory");                        \
    __builtin_amdgcn_sched_barrier(0);                                        \
    __builtin_amdgcn_s_setprio(1);                                            \
    MFMA16(QR, QC, AV, BV);                                                   \
    __builtin_amdgcn_s_setprio(0);                                            \
    TAIL;                                                                     \
    __builtin_amdgcn_s_barrier();

template<int LDA, int LDB, int LDC, int KTOT>
__device__ __forceinline__ void gemm256(
    const f16* __restrict__ A, const f16* __restrict__ B,
    f16* __restrict__ C, float scale, int m0, int n0)
{
    constexpr int NT = KTOT / 64;
    __shared__ f16 sA0[256 * 64];
    __shared__ f16 sB0[256 * 64];
    __shared__ f16 sA1[256 * 64];
    __shared__ f16 sB1[256 * 64];

    const int t = threadIdx.x;
    const int w = t >> 6, l = t & 63;
    const int fr = l & 15, fq = l >> 4;     // MFMA fragment row / k-chunk
    const int wr = w >> 2, wc = w & 3;      // wave row-group / col-group
    const int lr = l >> 3, lc = l & 7;      // stage window row / chunk
    const int swc = lc ^ lr;                // pre-swizzled SOURCE chunk
    const int sw0 = fq ^ (fr & 7);          // read swizzle, ks=0
    const int sw1 = (4 + fq) ^ (fr & 7);    // read swizzle, ks=1

    f32x4 acc[8][4] = {};

    auto stageA = [&](f16* buf, int half, int kt) {
#pragma unroll
        for (int i = 0; i < 2; ++i) {
            const int r0 = half * 128 + i * 64 + w * 8;
            const f16* g = A + (size_t)(m0 + r0 + lr) * LDA + kt * 64 + swc * 8;
            __builtin_amdgcn_global_load_lds((g_void*)g, (lds_void*)(buf + r0 * 64), 16, 0, 0);
        }
    };
    auto stageB = [&](f16* buf, int half, int kt) {
#pragma unroll
        for (int i = 0; i < 2; ++i) {
            const int r0 = half * 128 + i * 64 + w * 8;
            const f16* g = B + (size_t)(n0 + r0 + lr) * LDB + kt * 64 + swc * 8;
            __builtin_amdgcn_global_load_lds((g_void*)g, (lds_void*)(buf + r0 * 64), 16, 0, 0);
        }
    };

    // prologue: tile0 (4 halves) + tile1 (A0,B0) = 12 loads; drain tile0.
    stageA(sA0, 0, 0); stageB(sB0, 0, 0);
    stageA(sA0, 1, 0); stageB(sB0, 1, 0);
    if (NT > 1) { stageA(sA1, 0, 1); stageB(sB1, 0, 1); }
    asm volatile("s_waitcnt vmcnt(4)" ::: "memory");
    __builtin_amdgcn_s_barrier();

#pragma unroll
    for (int kt = 0; kt < NT; ++kt) {
        f16* cA = (kt & 1) ? sA1 : sA0;
        f16* cB = (kt & 1) ? sB1 : sB0;
        f16* nA = (kt & 1) ? sA0 : sA1;
        f16* nB = (kt & 1) ? sB0 : sB1;

        f16x8 av0[4][2], av1[4][2], bv0[2][2], bv1[2][2];

        // p0: read A0+B0 (12) -> Q00
        READ_A(av0, cA, 0);
        READ_B(bv0, cB, 0);
        PHASE_SYNC_MFMA(0, 0, av0, bv0,
            { if (kt + 1 < NT) stageA(nA, 1, kt + 1); }, {});

        // p1: read B1 (4), reuse av0 -> Q01
        READ_B(bv1, cB, 1);
        PHASE_SYNC_MFMA(0, 1, av0, bv1,
            { if (kt + 1 < NT) stageB(nB, 1, kt + 1); }, {});

        // p2: read A1 (8), reuse bv1 -> Q11
        READ_A(av1, cA, 1);
        PHASE_SYNC_MFMA(1, 1, av1, bv1,
            { if (kt + 2 < NT) stageA(cA, 0, kt + 2); }, {});

        // p3: ZERO reads, reuse av1+bv0 -> Q10; tile-end counted vmcnt
        PHASE_SYNC_MFMA(1, 0, av1, bv0,
            { if (kt + 2 < NT) stageB(cB, 0, kt + 2); },
            { if (kt + 2 < NT) { asm volatile("s_waitcnt vmcnt(4)" ::: "memory"); }
              else             { asm volatile("s_waitcnt vmcnt(0)" ::: "memory"); } });
    }

    // epilogue: interleaved mapping -> global C
#pragma unroll
    for (int ri = 0; ri < 8; ++ri)
#pragma unroll
        for (int cj = 0; cj < 4; ++cj)
#pragma unroll
            for (int rr = 0; rr < 4; ++rr) {
                const int row = m0 + (ri >> 2) * 128 + wr * 64 + (ri & 3) * 16 + fq * 4 + rr;
                const int col = n0 + (cj >> 1) * 128 + wc * 32 + (cj & 1) * 16 + fr;
                C[(size_t)row * LDC + col] = (f16)(acc[ri][cj][rr] * scale);
            }
}

// GEMM1: Yh[z] = f16( x[b] @ Wh[h] ), z=b*4+h. xcd=b. 256 blocks.
__global__ __launch_bounds__(512, 2) void k_g1(
    const f16* __restrict__ xfh, const f16* __restrict__ wTh,
    f16* __restrict__ Yh)
{
    const int i = blockIdx.x;
    const int b = i & 7;
    const int li = i >> 3;            // 0..31
    const int h = li >> 3;
    const int tile = li & 7;
    const int m0 = (tile >> 1) * 256;
    const int n0 = (tile & 1) * 256;
    const int z = b * 4 + h;
    gemm256<D_, D_, D_, D_>(
        xfh + (size_t)b * ND,
        wTh + (size_t)h * DD,
        Yh + (size_t)z * ND, 1.0f, m0, n0);
}

// GEMM2: S[z] = f16( Yh[z] @ xh[b]^T * scale ). xcd=b. 512 blocks.
__global__ __launch_bounds__(512, 2) void k_g2(
    const f16* __restrict__ Yh, const f16* __restrict__ xfh,
    f16* __restrict__ S)
{
    const int i = blockIdx.x;
    const int b = i & 7;
    const int li = i >> 3;           // 0..63
    const int h = li >> 4;
    const int tile = li & 15;
    const int m0 = (tile >> 2) * 256;
    const int n0 = (tile & 3) * 256;
    const int z = b * 4 + h;
    gemm256<D_, D_, N_, D_>(
        Yh + (size_t)z * ND,
        xfh + (size_t)b * ND,
        S + (size_t)z * NN, 0.044194173824159216f, m0, n0);
}

// GEMM4 split-K by head: part[z] = f16( P[z] @ xT[b]^T ). xcd=b. 256 blocks.
__global__ __launch_bounds__(512, 2) void k_g4(
    const f16* __restrict__ P, const f16* __restrict__ xT,
    f16* __restrict__ part)
{
    const int i = blockIdx.x;
    const int b = i & 7;
    const int li = i >> 3;            // 0..31
    const int h = li >> 3;
    const int tile = li & 7;
    const int m0 = (tile >> 1) * 256;
    const int n0 = (tile & 1) * 256;
    const int z = b * 4 + h;
    gemm256<N_, N_, D_, N_>(
        P + (size_t)z * NN,
        xT + (size_t)b * ND,
        part + (size_t)z * ND, 1.0f, m0, n0);
}

// Reduce: out[b] = 0.25 * sum_h part[b*4+h]   (f16 partials, 8 elems/thread)
__global__ __launch_bounds__(256) void k_reduce(
    const f16* __restrict__ part, float* __restrict__ out)
{
    const int i = blockIdx.x * 256 + threadIdx.x;
    const int b = i / (ND / 8);
    const int r = i - b * (ND / 8);
    const f16x8* p = (const f16x8*)part;
    f16x8 a0 = p[(size_t)(b * 4 + 0) * (ND / 8) + r];
    f16x8 a1 = p[(size_t)(b * 4 + 1) * (ND / 8) + r];
    f16x8 a2 = p[(size_t)(b * 4 + 2) * (ND / 8) + r];
    f16x8 a3 = p[(size_t)(b * 4 + 3) * (ND / 8) + r];
    float4 o0, o1;
    float* o = (float*)&o0;
#pragma unroll
    for (int k = 0; k < 4; ++k)
        o[k] = 0.25f * ((float)a0[k] + (float)a1[k] + (float)a2[k] + (float)a3[k]);
    o = (float*)&o1;
#pragma unroll
    for (int k = 0; k < 4; ++k)
        o[k] = 0.25f * ((float)a0[k+4] + (float)a1[k+4] + (float)a2[k+4] + (float)a3[k+4]);
    ((float4*)out)[(size_t)i * 2]     = o0;
    ((float4*)out)[(size_t)i * 2 + 1] = o1;
}

// Merged decomp: z<8 -> x-batch z (f16 hi + transposed hi); z>=8 -> W head
// z-8 (hi only + transpose). Grid (8,16,12); W part uses y<8 only.
__global__ __launch_bounds__(256) void decomp_xw(
    const float* __restrict__ x, const float* __restrict__ W,
    f16* __restrict__ xfh, f16* __restrict__ xT, f16* __restrict__ wTh)
{
    __shared__ f16 tile[64][65];
    __shared__ float tw[64][65];
    const int t = threadIdx.x;
    const int z = blockIdx.z;
    if (z < 8) {
        const int b = z, n0 = blockIdx.y * 64, d0 = blockIdx.x * 64;
        const float* xb = x + (size_t)b * ND;
#pragma unroll
        for (int p = 0; p < 16; ++p) {
            const int idx = t + p * 256;
            const int r = idx >> 6, c = idx & 63;
            const float v = xb[(size_t)(n0 + r) * D_ + d0 + c];
            const f16 h = (f16)v;
            xfh[(size_t)b * ND + (size_t)(n0 + r) * D_ + d0 + c] = h;
            tile[r][c] = h;
        }
        __syncthreads();
#pragma unroll
        for (int p = 0; p < 16; ++p) {
            const int idx = t + p * 256;
            const int r = idx >> 6, c = idx & 63;
            xT[(size_t)b * ND + (size_t)(d0 + r) * N_ + n0 + c] = tile[c][r];
        }
    } else {
        if (blockIdx.y >= 8) return;
        const int h = z - 8, d0 = blockIdx.y * 64, e0 = blockIdx.x * 64;
        const float* Wh = W + (size_t)h * DD;
#pragma unroll
        for (int p = 0; p < 16; ++p) {
            const int idx = t + p * 256;
            const int r = idx >> 6, c = idx & 63;
            tw[r][c] = Wh[(size_t)(d0 + r) * D_ + e0 + c];
        }
        __syncthreads();
#pragma unroll
        for (int p = 0; p < 16; ++p) {
            const int idx = t + p * 256;
            const int r = idx >> 6, c = idx & 63;
            wTh[(size_t)h * DD + (size_t)(e0 + r) * D_ + d0 + c] = (f16)tw[c][r];
        }
    }
}

// Barrier-free softmax, XCD-aligned: block i -> b = i&7 (same placement as
// the g2 blocks that wrote S[b's z-range]) so S reads hit the local L2.
// One wave per row, 4 rows/block. 8192 blocks.
__global__ __launch_bounds__(256) void softmax_wave(
    const f16* __restrict__ S, f16* __restrict__ P)
{
    const int wave = threadIdx.x >> 6;
    const int l = threadIdx.x & 63;
    const int i = blockIdx.x;
    const int b = i & 7;
    const int li = i >> 3;            // 0..1023
    const int h = li >> 8;            // 0..3
    const int rg = li & 255;          // 0..255 row-group (4 rows)
    const size_t row = (size_t)(b * 4 + h) * N_ + rg * 4 + wave;

    const f16x8* p = (const f16x8*)(S + row * N_);
    f16x8 v0 = p[l * 2], v1 = p[l * 2 + 1];

    float f[16];
#pragma unroll
    for (int k = 0; k < 8; ++k) { f[k] = (float)v0[k]; f[k + 8] = (float)v1[k]; }

    float m = f[0];
#pragma unroll
    for (int k = 1; k < 16; ++k) m = fmaxf(m, f[k]);
#pragma unroll
    for (int o = 32; o > 0; o >>= 1) m = fmaxf(m, __shfl_xor(m, o));

    float s = 0.f;
#pragma unroll
    for (int k = 0; k < 16; ++k) { f[k] = __expf(f[k] - m); s += f[k]; }
#pragma unroll
    for (int o = 32; o > 0; o >>= 1) s += __shfl_xor(s, o);

    const float inv = 1.0f / s;
    f16x8 o0, o1;
#pragma unroll
    for (int k = 0; k < 8; ++k) {
        o0[k] = (f16)(f[k] * inv);
        o1[k] = (f16)(f[k + 8] * inv);
    }
    f16x8* q = (f16x8*)(P + row * N_);
    q[l * 2] = o0;
    q[l * 2 + 1] = o1;
}

extern "C" void kernel_launch(void* const* d_in, const int* in_sizes, int n_in,
                              void* d_out, int out_size, void* d_ws, size_t ws_size,
                              hipStream_t stream) {
    const float* x = (const float*)d_in[0];   // [8,1024,512]
    const float* W = (const float*)d_in[1];   // [4,512,512]
    float* out = (float*)d_out;               // [8,1024,512]

    // workspace layout (proven footprint)
    char* ws = (char*)d_ws;
    const size_t MB = 1024 * 1024;
    f16*   xfh = (f16*)(ws + 0 * MB);     // 8 MiB
    f16*   xT  = (f16*)(ws + 8 * MB);     // 8 MiB
    f16*   wTh = (f16*)(ws + 16 * MB);    // 2 MiB
    f16*   Yh  = (f16*)(ws + 20 * MB);    // 32 MiB (full batch, 32 z)
    f16*   S   = (f16*)(ws + 52 * MB);    // 64 MiB (full batch, f16)
    f16*   P   = (f16*)(ws + 116 * MB);   // 64 MiB (full batch, f16)
    f16*   part = S;                      // g4 partials (32 MiB) reuse S

    decomp_xw<<<dim3(8, 16, 12), 256, 0, stream>>>(x, W, xfh, xT, wTh);

    k_g1<<<dim3(256), 512, 0, stream>>>(xfh, wTh, Yh);
    k_g2<<<dim3(512), 512, 0, stream>>>(Yh, xfh, S);
    softmax_wave<<<dim3(B_ * H_ * N_ / 4), 256, 0, stream>>>(S, P);
    k_g4<<<dim3(256), 512, 0, stream>>>(P, xT, part);
    k_reduce<<<dim3((B_ * ND / 8) / 256), 256, 0, stream>>>(part, out);
}

// Round 5
// 171.312 us; speedup vs baseline: 1.2175x; 1.1107x over previous
//
#include <hip/hip_runtime.h>
#include <math.h>

#define B_ 8
#define N_ 1024
#define D_ 512
#define H_ 4
#define ND (N_ * D_)      // 524288
#define DD (D_ * D_)      // 262144
#define NN (N_ * N_)      // 1048576

typedef _Float16 f16;
typedef f16 f16x8 __attribute__((ext_vector_type(8)));
typedef float f32x4 __attribute__((ext_vector_type(4)));

typedef __attribute__((address_space(3))) void lds_void;
typedef __attribute__((address_space(1))) void g_void;

// =====================================================================
// 256x256 8-phase GEMM core (R4-proven: T2 swizzle + cross-phase reg
// reuse, 24 ds_read_b128/K-tile, counted vmcnt, setprio). Unchanged.
// =====================================================================

#define MFMA16(QR, QC, AV, BV)                                                \
    _Pragma("unroll")                                                         \
    for (int i_ = 0; i_ < 4; ++i_)                                            \
        _Pragma("unroll")                                                     \
        for (int j_ = 0; j_ < 2; ++j_) {                                      \
            acc[(QR)*4+i_][(QC)*2+j_] = __builtin_amdgcn_mfma_f32_16x16x32_f16(AV[i_][0], BV[j_][0], acc[(QR)*4+i_][(QC)*2+j_], 0, 0, 0); \
            acc[(QR)*4+i_][(QC)*2+j_] = __builtin_amdgcn_mfma_f32_16x16x32_f16(AV[i_][1], BV[j_][1], acc[(QR)*4+i_][(QC)*2+j_], 0, 0, 0); \
        }

#define READ_A(AV, PA, HALF)                                                  \
    _Pragma("unroll")                                                         \
    for (int i_ = 0; i_ < 4; ++i_) {                                          \
        const int ra_ = (HALF) * 128 + wr * 64 + i_ * 16 + fr;                \
        AV[i_][0] = *(const f16x8*)(PA + ra_ * 64 + sw0 * 8);                 \
        AV[i_][1] = *(const f16x8*)(PA + ra_ * 64 + sw1 * 8);                 \
    }

#define READ_B(BV, PB, HALF)                                                  \
    _Pragma("unroll")                                                         \
    for (int j_ = 0; j_ < 2; ++j_) {                                          \
        const int rb_ = (HALF) * 128 + wc * 32 + j_ * 16 + fr;                \
        BV[j_][0] = *(const f16x8*)(PB + rb_ * 64 + sw0 * 8);                 \
        BV[j_][1] = *(const f16x8*)(PB + rb_ * 64 + sw1 * 8);                 \
    }

#define PHASE_SYNC_MFMA(QR, QC, AV, BV, STAGE, TAIL)                          \
    __builtin_amdgcn_sched_barrier(0);                                        \
    STAGE;                                                                    \
    __builtin_amdgcn_s_barrier();                                             \
    asm volatile("s_waitcnt lgkmcnt(0)" ::: "memory");                        \
    __builtin_amdgcn_sched_barrier(0);                                        \
    __builtin_amdgcn_s_setprio(1);                                            \
    MFMA16(QR, QC, AV, BV);                                                   \
    __builtin_amdgcn_s_setprio(0);                                            \
    TAIL;                                                                     \
    __builtin_amdgcn_s_barrier();

template<int LDA, int LDB, int LDC, int KTOT>
__device__ __forceinline__ void gemm256(
    const f16* __restrict__ A, const f16* __restrict__ B,
    f16* __restrict__ C, float scale, int m0, int n0)
{
    constexpr int NT = KTOT / 64;
    __shared__ f16 sA0[256 * 64];
    __shared__ f16 sB0[256 * 64];
    __shared__ f16 sA1[256 * 64];
    __shared__ f16 sB1[256 * 64];

    const int t = threadIdx.x;
    const int w = t >> 6, l = t & 63;
    const int fr = l & 15, fq = l >> 4;     // MFMA fragment row / k-chunk
    const int wr = w >> 2, wc = w & 3;      // wave row-group / col-group
    const int lr = l >> 3, lc = l & 7;      // stage window row / chunk
    const int swc = lc ^ lr;                // pre-swizzled SOURCE chunk
    const int sw0 = fq ^ (fr & 7);          // read swizzle, ks=0
    const int sw1 = (4 + fq) ^ (fr & 7);    // read swizzle, ks=1

    f32x4 acc[8][4] = {};

    auto stageA = [&](f16* buf, int half, int kt) {
#pragma unroll
        for (int i = 0; i < 2; ++i) {
            const int r0 = half * 128 + i * 64 + w * 8;
            const f16* g = A + (size_t)(m0 + r0 + lr) * LDA + kt * 64 + swc * 8;
            __builtin_amdgcn_global_load_lds((g_void*)g, (lds_void*)(buf + r0 * 64), 16, 0, 0);
        }
    };
    auto stageB = [&](f16* buf, int half, int kt) {
#pragma unroll
        for (int i = 0; i < 2; ++i) {
            const int r0 = half * 128 + i * 64 + w * 8;
            const f16* g = B + (size_t)(n0 + r0 + lr) * LDB + kt * 64 + swc * 8;
            __builtin_amdgcn_global_load_lds((g_void*)g, (lds_void*)(buf + r0 * 64), 16, 0, 0);
        }
    };

    // prologue: tile0 (4 halves) + tile1 (A0,B0) = 12 loads; drain tile0.
    stageA(sA0, 0, 0); stageB(sB0, 0, 0);
    stageA(sA0, 1, 0); stageB(sB0, 1, 0);
    if (NT > 1) { stageA(sA1, 0, 1); stageB(sB1, 0, 1); }
    asm volatile("s_waitcnt vmcnt(4)" ::: "memory");
    __builtin_amdgcn_s_barrier();

#pragma unroll
    for (int kt = 0; kt < NT; ++kt) {
        f16* cA = (kt & 1) ? sA1 : sA0;
        f16* cB = (kt & 1) ? sB1 : sB0;
        f16* nA = (kt & 1) ? sA0 : sA1;
        f16* nB = (kt & 1) ? sB0 : sB1;

        f16x8 av0[4][2], av1[4][2], bv0[2][2], bv1[2][2];

        // p0: read A0+B0 (12) -> Q00
        READ_A(av0, cA, 0);
        READ_B(bv0, cB, 0);
        PHASE_SYNC_MFMA(0, 0, av0, bv0,
            { if (kt + 1 < NT) stageA(nA, 1, kt + 1); }, {});

        // p1: read B1 (4), reuse av0 -> Q01
        READ_B(bv1, cB, 1);
        PHASE_SYNC_MFMA(0, 1, av0, bv1,
            { if (kt + 1 < NT) stageB(nB, 1, kt + 1); }, {});

        // p2: read A1 (8), reuse bv1 -> Q11
        READ_A(av1, cA, 1);
        PHASE_SYNC_MFMA(1, 1, av1, bv1,
            { if (kt + 2 < NT) stageA(cA, 0, kt + 2); }, {});

        // p3: ZERO reads, reuse av1+bv0 -> Q10; tile-end counted vmcnt
        PHASE_SYNC_MFMA(1, 0, av1, bv0,
            { if (kt + 2 < NT) stageB(cB, 0, kt + 2); },
            { if (kt + 2 < NT) { asm volatile("s_waitcnt vmcnt(4)" ::: "memory"); }
              else             { asm volatile("s_waitcnt vmcnt(0)" ::: "memory"); } });
    }

    // epilogue: interleaved mapping -> global C
#pragma unroll
    for (int ri = 0; ri < 8; ++ri)
#pragma unroll
        for (int cj = 0; cj < 4; ++cj)
#pragma unroll
            for (int rr = 0; rr < 4; ++rr) {
                const int row = m0 + (ri >> 2) * 128 + wr * 64 + (ri & 3) * 16 + fq * 4 + rr;
                const int col = n0 + (cj >> 1) * 128 + wc * 32 + (cj & 1) * 16 + fr;
                C[(size_t)row * LDC + col] = (f16)(acc[ri][cj][rr] * scale);
            }
}

// =====================================================================
// R0-proven 128x128 single-tile core, f32 output (for the shrunken
// final GEMM): 2-barrier BK=32 K-loop, global_load_lds w16.
// =====================================================================
template<int LDA, int LDB, int LDC, int KTOT>
__device__ __forceinline__ void single_core_f32(
    const f16* __restrict__ A, const f16* __restrict__ B0,
    float* __restrict__ C, int n0, int c0)
{
    __shared__ f16 sA[128 * 32];
    __shared__ f16 sB0[128 * 32];

    const int t = threadIdx.x;
    const int w = t >> 6;
    const int l = t & 63;
    const int lrow = l >> 2;
    const int lch  = l & 3;
    const int wr = w >> 1, wc = w & 1;
    const int fr = l & 15;
    const int fq = l >> 4;

    f32x4 acc[4][4] = {};

    for (int k0 = 0; k0 < KTOT; k0 += 32) {
#pragma unroll
        for (int i = 0; i < 2; ++i) {
            const int rb  = w * 2 + i;
            const int row = rb * 16 + lrow;
            const f16* ga = A + (size_t)(n0 + row) * LDA + k0 + lch * 8;
            __builtin_amdgcn_global_load_lds((g_void*)ga, (lds_void*)(sA + rb * 512), 16, 0, 0);
            const f16* gb0 = B0 + (size_t)(c0 + row) * LDB + k0 + lch * 8;
            __builtin_amdgcn_global_load_lds((g_void*)gb0, (lds_void*)(sB0 + rb * 512), 16, 0, 0);
        }
        __syncthreads();

        f16x8 a[4], b0[4];
#pragma unroll
        for (int i = 0; i < 4; ++i) {
            a[i]  = *(const f16x8*)(sA  + (wr * 64 + i * 16 + fr) * 32 + fq * 8);
            b0[i] = *(const f16x8*)(sB0 + (wc * 64 + i * 16 + fr) * 32 + fq * 8);
        }

#pragma unroll
        for (int i = 0; i < 4; ++i)
#pragma unroll
            for (int j = 0; j < 4; ++j)
                acc[i][j] = __builtin_amdgcn_mfma_f32_16x16x32_f16(a[i], b0[j], acc[i][j], 0, 0, 0);
        __syncthreads();
    }

#pragma unroll
    for (int i = 0; i < 4; ++i)
#pragma unroll
        for (int j = 0; j < 4; ++j)
#pragma unroll
            for (int r = 0; r < 4; ++r) {
                const int row = n0 + wr * 64 + i * 16 + fq * 4 + r;
                const int col = c0 + wc * 64 + j * 16 + fr;
                C[(size_t)row * LDC + col] = acc[i][j][r];
            }
}

// GEMM1: Yh[z] = f16( x[b] @ Wh[h] ), z=b*4+h. xcd=b. 256 blocks.
__global__ __launch_bounds__(512, 2) void k_g1(
    const f16* __restrict__ xfh, const f16* __restrict__ wTh,
    f16* __restrict__ Yh)
{
    const int i = blockIdx.x;
    const int b = i & 7;
    const int li = i >> 3;            // 0..31
    const int h = li >> 3;
    const int tile = li & 7;
    const int m0 = (tile >> 1) * 256;
    const int n0 = (tile & 1) * 256;
    const int z = b * 4 + h;
    gemm256<D_, D_, D_, D_>(
        xfh + (size_t)b * ND,
        wTh + (size_t)h * DD,
        Yh + (size_t)z * ND, 1.0f, m0, n0);
}

// GEMM2: S[z] = f16( Yh[z] @ xh[b]^T * scale ). xcd=b. 512 blocks.
__global__ __launch_bounds__(512, 2) void k_g2(
    const f16* __restrict__ Yh, const f16* __restrict__ xfh,
    f16* __restrict__ S)
{
    const int i = blockIdx.x;
    const int b = i & 7;
    const int li = i >> 3;           // 0..63
    const int h = li >> 4;
    const int tile = li & 15;
    const int m0 = (tile >> 2) * 256;
    const int n0 = (tile & 3) * 256;
    const int z = b * 4 + h;
    gemm256<D_, D_, N_, D_>(
        Yh + (size_t)z * ND,
        xfh + (size_t)b * ND,
        S + (size_t)z * NN, 0.044194173824159216f, m0, n0);
}

// Softmax + head-mean: Pbar[b] = 0.25 * sum_h softmax(S[b*4+h]).
// mean_h commutes with the final GEMM: out = (mean_h P_h) @ x.
// One wave per row; each wave processes the SAME row across all 4 heads
// and writes one Pbar row (f16, 0.25 folded in). XCD-aligned b=i&7.
// 2048 blocks.
__global__ __launch_bounds__(256) void softmax_mean(
    const f16* __restrict__ S, f16* __restrict__ Pb)
{
    const int wave = threadIdx.x >> 6;
    const int l = threadIdx.x & 63;
    const int i = blockIdx.x;
    const int b = i & 7;
    const int rg = i >> 3;            // 0..255
    const int row = rg * 4 + wave;    // 0..1023

    float o[16];
#pragma unroll
    for (int k = 0; k < 16; ++k) o[k] = 0.f;

#pragma unroll
    for (int h = 0; h < 4; ++h) {
        const f16x8* p = (const f16x8*)(S + ((size_t)(b * 4 + h) * N_ + row) * N_);
        f16x8 v0 = p[l * 2], v1 = p[l * 2 + 1];
        float f[16];
#pragma unroll
        for (int k = 0; k < 8; ++k) { f[k] = (float)v0[k]; f[k + 8] = (float)v1[k]; }
        float m = f[0];
#pragma unroll
        for (int k = 1; k < 16; ++k) m = fmaxf(m, f[k]);
#pragma unroll
        for (int off = 32; off > 0; off >>= 1) m = fmaxf(m, __shfl_xor(m, off));
        float s = 0.f;
#pragma unroll
        for (int k = 0; k < 16; ++k) { f[k] = __expf(f[k] - m); s += f[k]; }
#pragma unroll
        for (int off = 32; off > 0; off >>= 1) s += __shfl_xor(s, off);
        const float q = 0.25f / s;
#pragma unroll
        for (int k = 0; k < 16; ++k) o[k] += f[k] * q;
    }

    f16x8 o0, o1;
#pragma unroll
    for (int k = 0; k < 8; ++k) { o0[k] = (f16)o[k]; o1[k] = (f16)o[k + 8]; }
    f16x8* qp = (f16x8*)(Pb + ((size_t)b * N_ + row) * N_);
    qp[l * 2] = o0;
    qp[l * 2 + 1] = o1;
}

// Final GEMM (4x smaller than old g4): out[b] = Pbar[b] @ xT[b]^T, f32
// direct to output — no partials, no reduce. 256 blocks (32 tiles/b).
__global__ __launch_bounds__(256, 2) void k_g4b(
    const f16* __restrict__ Pb, const f16* __restrict__ xT,
    float* __restrict__ out)
{
    const int i = blockIdx.x;
    const int b = i & 7;
    const int li = i >> 3;            // 0..31
    const int m0 = (li >> 2) * 128;   // 8 m-tiles
    const int d0 = (li & 3) * 128;    // 4 n-tiles
    single_core_f32<N_, N_, D_, N_>(
        Pb + (size_t)b * NN,
        xT + (size_t)b * ND,
        out + (size_t)b * ND, m0, d0);
}

// Merged decomp: z<8 -> x-batch z (f16 hi + transposed hi); z>=8 -> W head
// z-8 (hi only + transpose). Grid (8,16,12); W part uses y<8 only.
__global__ __launch_bounds__(256) void decomp_xw(
    const float* __restrict__ x, const float* __restrict__ W,
    f16* __restrict__ xfh, f16* __restrict__ xT, f16* __restrict__ wTh)
{
    __shared__ f16 tile[64][65];
    __shared__ float tw[64][65];
    const int t = threadIdx.x;
    const int z = blockIdx.z;
    if (z < 8) {
        const int b = z, n0 = blockIdx.y * 64, d0 = blockIdx.x * 64;
        const float* xb = x + (size_t)b * ND;
#pragma unroll
        for (int p = 0; p < 16; ++p) {
            const int idx = t + p * 256;
            const int r = idx >> 6, c = idx & 63;
            const float v = xb[(size_t)(n0 + r) * D_ + d0 + c];
            const f16 h = (f16)v;
            xfh[(size_t)b * ND + (size_t)(n0 + r) * D_ + d0 + c] = h;
            tile[r][c] = h;
        }
        __syncthreads();
#pragma unroll
        for (int p = 0; p < 16; ++p) {
            const int idx = t + p * 256;
            const int r = idx >> 6, c = idx & 63;
            xT[(size_t)b * ND + (size_t)(d0 + r) * N_ + n0 + c] = tile[c][r];
        }
    } else {
        if (blockIdx.y >= 8) return;
        const int h = z - 8, d0 = blockIdx.y * 64, e0 = blockIdx.x * 64;
        const float* Wh = W + (size_t)h * DD;
#pragma unroll
        for (int p = 0; p < 16; ++p) {
            const int idx = t + p * 256;
            const int r = idx >> 6, c = idx & 63;
            tw[r][c] = Wh[(size_t)(d0 + r) * D_ + e0 + c];
        }
        __syncthreads();
#pragma unroll
        for (int p = 0; p < 16; ++p) {
            const int idx = t + p * 256;
            const int r = idx >> 6, c = idx & 63;
            wTh[(size_t)h * DD + (size_t)(e0 + r) * D_ + d0 + c] = (f16)tw[c][r];
        }
    }
}

extern "C" void kernel_launch(void* const* d_in, const int* in_sizes, int n_in,
                              void* d_out, int out_size, void* d_ws, size_t ws_size,
                              hipStream_t stream) {
    const float* x = (const float*)d_in[0];   // [8,1024,512]
    const float* W = (const float*)d_in[1];   // [4,512,512]
    float* out = (float*)d_out;               // [8,1024,512]

    // workspace layout
    char* ws = (char*)d_ws;
    const size_t MB = 1024 * 1024;
    f16*   xfh = (f16*)(ws + 0 * MB);     // 8 MiB
    f16*   xT  = (f16*)(ws + 8 * MB);     // 8 MiB
    f16*   wTh = (f16*)(ws + 16 * MB);    // 2 MiB
    f16*   Yh  = (f16*)(ws + 20 * MB);    // 32 MiB (full batch, 32 z)
    f16*   S   = (f16*)(ws + 52 * MB);    // 64 MiB (full batch, f16)
    f16*   Pb  = (f16*)(ws + 116 * MB);   // 16 MiB (head-mean P, 8 b)

    decomp_xw<<<dim3(8, 16, 12), 256, 0, stream>>>(x, W, xfh, xT, wTh);

    k_g1<<<dim3(256), 512, 0, stream>>>(xfh, wTh, Yh);
    k_g2<<<dim3(512), 512, 0, stream>>>(Yh, xfh, S);
    softmax_mean<<<dim3(2048), 256, 0, stream>>>(S, Pb);
    k_g4b<<<dim3(256), 256, 0, stream>>>(Pb, xT, out);
}

// Round 6
// 169.622 us; speedup vs baseline: 1.2297x; 1.0100x over previous
//
#include <hip/hip_runtime.h>
#include <math.h>

#define B_ 8
#define N_ 1024
#define D_ 512
#define H_ 4
#define ND (N_ * D_)      // 524288
#define DD (D_ * D_)      // 262144
#define NN (N_ * N_)      // 1048576

typedef _Float16 f16;
typedef f16 f16x8 __attribute__((ext_vector_type(8)));
typedef float f32x4 __attribute__((ext_vector_type(4)));

typedef __attribute__((address_space(3))) void lds_void;
typedef __attribute__((address_space(1))) void g_void;

// =====================================================================
// 256x256 8-phase GEMM core with PHASE-LEVEL READ-AHEAD:
// each phase = { barrier; lgkmcnt(0); MFMA half1 (frags read during the
// PREVIOUS phase); issue next phase's ds_reads; stage; MFMA half2 } —
// the ds_reads run on the LDS pipe while MFMAs occupy the matrix pipe.
// Fragment double-buffer: X,Y = A-half frags; U,V = B-half frags, roles
// alternating per tile (2-tile unrolled body). ONE barrier per phase
// (every LDS region is read >=2 barriers before its re-stage; counted
// vmcnt(4) invariant: at tile-t entry exactly A0,B0 of t+1 in flight).
// T2 swizzle unchanged (read chunk ^ row, pre-swizzled global source).
// =====================================================================

#define MFMA8(QR, QC, AV, BV, IB)                                             \
    _Pragma("unroll")                                                         \
    for (int i_ = 0; i_ < 2; ++i_) {                                          \
        const int ii_ = (IB) + i_;                                            \
        _Pragma("unroll")                                                     \
        for (int j_ = 0; j_ < 2; ++j_) {                                      \
            acc[(QR)*4+ii_][(QC)*2+j_] = __builtin_amdgcn_mfma_f32_16x16x32_f16(AV[ii_][0], BV[j_][0], acc[(QR)*4+ii_][(QC)*2+j_], 0, 0, 0); \
            acc[(QR)*4+ii_][(QC)*2+j_] = __builtin_amdgcn_mfma_f32_16x16x32_f16(AV[ii_][1], BV[j_][1], acc[(QR)*4+ii_][(QC)*2+j_], 0, 0, 0); \
        }                                                                     \
    }

#define READ_A(AV, PA, HALF)                                                  \
    _Pragma("unroll")                                                         \
    for (int i_ = 0; i_ < 4; ++i_) {                                          \
        const int ra_ = (HALF) * 128 + wr * 64 + i_ * 16 + fr;                \
        AV[i_][0] = *(const f16x8*)(PA + ra_ * 64 + sw0 * 8);                 \
        AV[i_][1] = *(const f16x8*)(PA + ra_ * 64 + sw1 * 8);                 \
    }

#define READ_B(BV, PB, HALF)                                                  \
    _Pragma("unroll")                                                         \
    for (int j_ = 0; j_ < 2; ++j_) {                                          \
        const int rb_ = (HALF) * 128 + wc * 32 + j_ * 16 + fr;                \
        BV[j_][0] = *(const f16x8*)(PB + rb_ * 64 + sw0 * 8);                 \
        BV[j_][1] = *(const f16x8*)(PB + rb_ * 64 + sw1 * 8);                 \
    }

#define PHASE_RA(QR, QC, AV, BV, READS, STAGE, TAIL)                          \
    __builtin_amdgcn_s_barrier();                                             \
    asm volatile("s_waitcnt lgkmcnt(0)" ::: "memory");                        \
    __builtin_amdgcn_sched_barrier(0);                                        \
    __builtin_amdgcn_s_setprio(1);                                            \
    MFMA8(QR, QC, AV, BV, 0);                                                 \
    __builtin_amdgcn_s_setprio(0);                                            \
    __builtin_amdgcn_sched_barrier(0);                                        \
    READS;                                                                    \
    __builtin_amdgcn_sched_barrier(0);                                        \
    STAGE;                                                                    \
    __builtin_amdgcn_s_setprio(1);                                            \
    MFMA8(QR, QC, AV, BV, 2);                                                 \
    __builtin_amdgcn_s_setprio(0);                                            \
    TAIL;

template<int LDA, int LDB, int LDC, int KTOT>
__device__ __forceinline__ void gemm256(
    const f16* __restrict__ A, const f16* __restrict__ B,
    f16* __restrict__ C, float scale, int m0, int n0)
{
    constexpr int NT = KTOT / 64;
    static_assert(NT >= 2 && (NT % 2) == 0, "NT must be even");
    __shared__ f16 sA0[256 * 64];
    __shared__ f16 sB0[256 * 64];
    __shared__ f16 sA1[256 * 64];
    __shared__ f16 sB1[256 * 64];

    const int t = threadIdx.x;
    const int w = t >> 6, l = t & 63;
    const int fr = l & 15, fq = l >> 4;     // MFMA fragment row / k-chunk
    const int wr = w >> 2, wc = w & 3;      // wave row-group / col-group
    const int lr = l >> 3, lc = l & 7;      // stage window row / chunk
    const int swc = lc ^ lr;                // pre-swizzled SOURCE chunk
    const int sw0 = fq ^ (fr & 7);          // read swizzle, ks=0
    const int sw1 = (4 + fq) ^ (fr & 7);    // read swizzle, ks=1

    f32x4 acc[8][4] = {};

    auto stageA = [&](f16* buf, int half, int kt) {
#pragma unroll
        for (int i = 0; i < 2; ++i) {
            const int r0 = half * 128 + i * 64 + w * 8;
            const f16* g = A + (size_t)(m0 + r0 + lr) * LDA + kt * 64 + swc * 8;
            __builtin_amdgcn_global_load_lds((g_void*)g, (lds_void*)(buf + r0 * 64), 16, 0, 0);
        }
    };
    auto stageB = [&](f16* buf, int half, int kt) {
#pragma unroll
        for (int i = 0; i < 2; ++i) {
            const int r0 = half * 128 + i * 64 + w * 8;
            const f16* g = B + (size_t)(n0 + r0 + lr) * LDB + kt * 64 + swc * 8;
            __builtin_amdgcn_global_load_lds((g_void*)g, (lds_void*)(buf + r0 * 64), 16, 0, 0);
        }
    };

    // prologue: tile0 fully + tile1 A0,B0 = 12 loads; drain tile0
    // (vmcnt(4) leaves exactly tile1's A0,B0 in flight = loop invariant).
    stageA(sA0, 0, 0); stageB(sB0, 0, 0);
    stageA(sA0, 1, 0); stageB(sB0, 1, 0);
    stageA(sA1, 0, 1); stageB(sB1, 0, 1);
    asm volatile("s_waitcnt vmcnt(4)" ::: "memory");
    __builtin_amdgcn_s_barrier();

    f16x8 X[4][2], Y[4][2], U[2][2], V[2][2];
    // initial frags for tile0 phase0
    READ_A(X, sA0, 0);
    READ_B(U, sB0, 0);

#define TAILCNT(KT)                                                           \
    { if ((KT) + 2 < NT) { asm volatile("s_waitcnt vmcnt(4)" ::: "memory"); } \
      else               { asm volatile("s_waitcnt vmcnt(0)" ::: "memory"); } }

#pragma unroll
    for (int tt = 0; tt < NT / 2; ++tt) {
        const int te = 2 * tt, to = 2 * tt + 1;
        // ---- even tile te: bufs sA0/sB0; A0->X, B0->U live ----
        PHASE_RA(0, 0, X, U, { READ_B(V, sB0, 1); },
                 { if (te + 1 < NT) stageA(sA1, 1, te + 1); }, {});
        PHASE_RA(0, 1, X, V, { READ_A(Y, sA0, 1); },
                 { if (te + 1 < NT) stageB(sB1, 1, te + 1); }, {});
        PHASE_RA(1, 1, Y, V, {},
                 { if (te + 2 < NT) stageA(sA0, 0, te + 2); }, {});
        PHASE_RA(1, 0, Y, U,
                 { if (te + 1 < NT) { READ_A(X, sA1, 0); READ_B(V, sB1, 0); } },
                 { if (te + 2 < NT) stageB(sB0, 0, te + 2); }, TAILCNT(te));
        // ---- odd tile to: bufs sA1/sB1; A0'->X, B0'->V live ----
        PHASE_RA(0, 0, X, V, { READ_B(U, sB1, 1); },
                 { if (to + 1 < NT) stageA(sA0, 1, to + 1); }, {});
        PHASE_RA(0, 1, X, U, { READ_A(Y, sA1, 1); },
                 { if (to + 1 < NT) stageB(sB0, 1, to + 1); }, {});
        PHASE_RA(1, 1, Y, U, {},
                 { if (to + 2 < NT) stageA(sA1, 0, to + 2); }, {});
        PHASE_RA(1, 0, Y, V,
                 { if (to + 1 < NT) { READ_A(X, sA0, 0); READ_B(U, sB0, 0); } },
                 { if (to + 2 < NT) stageB(sB1, 0, to + 2); }, TAILCNT(to));
    }
#undef TAILCNT

    // epilogue: interleaved mapping -> global C
#pragma unroll
    for (int ri = 0; ri < 8; ++ri)
#pragma unroll
        for (int cj = 0; cj < 4; ++cj)
#pragma unroll
            for (int rr = 0; rr < 4; ++rr) {
                const int row = m0 + (ri >> 2) * 128 + wr * 64 + (ri & 3) * 16 + fq * 4 + rr;
                const int col = n0 + (cj >> 1) * 128 + wc * 32 + (cj & 1) * 16 + fr;
                C[(size_t)row * LDC + col] = (f16)(acc[ri][cj][rr] * scale);
            }
}

// =====================================================================
// R0-proven 128x128 single-tile core, f32 output (final GEMM).
// =====================================================================
template<int LDA, int LDB, int LDC, int KTOT>
__device__ __forceinline__ void single_core_f32(
    const f16* __restrict__ A, const f16* __restrict__ B0,
    float* __restrict__ C, int n0, int c0)
{
    __shared__ f16 sA[128 * 32];
    __shared__ f16 sB0[128 * 32];

    const int t = threadIdx.x;
    const int w = t >> 6;
    const int l = t & 63;
    const int lrow = l >> 2;
    const int lch  = l & 3;
    const int wr = w >> 1, wc = w & 1;
    const int fr = l & 15;
    const int fq = l >> 4;

    f32x4 acc[4][4] = {};

    for (int k0 = 0; k0 < KTOT; k0 += 32) {
#pragma unroll
        for (int i = 0; i < 2; ++i) {
            const int rb  = w * 2 + i;
            const int row = rb * 16 + lrow;
            const f16* ga = A + (size_t)(n0 + row) * LDA + k0 + lch * 8;
            __builtin_amdgcn_global_load_lds((g_void*)ga, (lds_void*)(sA + rb * 512), 16, 0, 0);
            const f16* gb0 = B0 + (size_t)(c0 + row) * LDB + k0 + lch * 8;
            __builtin_amdgcn_global_load_lds((g_void*)gb0, (lds_void*)(sB0 + rb * 512), 16, 0, 0);
        }
        __syncthreads();

        f16x8 a[4], b0[4];
#pragma unroll
        for (int i = 0; i < 4; ++i) {
            a[i]  = *(const f16x8*)(sA  + (wr * 64 + i * 16 + fr) * 32 + fq * 8);
            b0[i] = *(const f16x8*)(sB0 + (wc * 64 + i * 16 + fr) * 32 + fq * 8);
        }

#pragma unroll
        for (int i = 0; i < 4; ++i)
#pragma unroll
            for (int j = 0; j < 4; ++j)
                acc[i][j] = __builtin_amdgcn_mfma_f32_16x16x32_f16(a[i], b0[j], acc[i][j], 0, 0, 0);
        __syncthreads();
    }

#pragma unroll
    for (int i = 0; i < 4; ++i)
#pragma unroll
        for (int j = 0; j < 4; ++j)
#pragma unroll
            for (int r = 0; r < 4; ++r) {
                const int row = n0 + wr * 64 + i * 16 + fq * 4 + r;
                const int col = c0 + wc * 64 + j * 16 + fr;
                C[(size_t)row * LDC + col] = acc[i][j][r];
            }
}

// GEMM1: Yh[z] = f16( x[b] @ Wh[h] ), z=b*4+h. xcd=b. 256 blocks.
__global__ __launch_bounds__(512, 2) void k_g1(
    const f16* __restrict__ xfh, const f16* __restrict__ wTh,
    f16* __restrict__ Yh)
{
    const int i = blockIdx.x;
    const int b = i & 7;
    const int li = i >> 3;            // 0..31
    const int h = li >> 3;
    const int tile = li & 7;
    const int m0 = (tile >> 1) * 256;
    const int n0 = (tile & 1) * 256;
    const int z = b * 4 + h;
    gemm256<D_, D_, D_, D_>(
        xfh + (size_t)b * ND,
        wTh + (size_t)h * DD,
        Yh + (size_t)z * ND, 1.0f, m0, n0);
}

// GEMM2: S[z] = f16( Yh[z] @ xh[b]^T * scale ). xcd=b. 512 blocks.
__global__ __launch_bounds__(512, 2) void k_g2(
    const f16* __restrict__ Yh, const f16* __restrict__ xfh,
    f16* __restrict__ S)
{
    const int i = blockIdx.x;
    const int b = i & 7;
    const int li = i >> 3;           // 0..63
    const int h = li >> 4;
    const int tile = li & 15;
    const int m0 = (tile >> 2) * 256;
    const int n0 = (tile & 3) * 256;
    const int z = b * 4 + h;
    gemm256<D_, D_, N_, D_>(
        Yh + (size_t)z * ND,
        xfh + (size_t)b * ND,
        S + (size_t)z * NN, 0.044194173824159216f, m0, n0);
}

// Softmax + head-mean: Pbar[b] = 0.25 * sum_h softmax(S[b*4+h]).
// 2048 blocks, one wave per row.
__global__ __launch_bounds__(256) void softmax_mean(
    const f16* __restrict__ S, f16* __restrict__ Pb)
{
    const int wave = threadIdx.x >> 6;
    const int l = threadIdx.x & 63;
    const int i = blockIdx.x;
    const int b = i & 7;
    const int rg = i >> 3;            // 0..255
    const int row = rg * 4 + wave;    // 0..1023

    float o[16];
#pragma unroll
    for (int k = 0; k < 16; ++k) o[k] = 0.f;

#pragma unroll
    for (int h = 0; h < 4; ++h) {
        const f16x8* p = (const f16x8*)(S + ((size_t)(b * 4 + h) * N_ + row) * N_);
        f16x8 v0 = p[l * 2], v1 = p[l * 2 + 1];
        float f[16];
#pragma unroll
        for (int k = 0; k < 8; ++k) { f[k] = (float)v0[k]; f[k + 8] = (float)v1[k]; }
        float m = f[0];
#pragma unroll
        for (int k = 1; k < 16; ++k) m = fmaxf(m, f[k]);
#pragma unroll
        for (int off = 32; off > 0; off >>= 1) m = fmaxf(m, __shfl_xor(m, off));
        float s = 0.f;
#pragma unroll
        for (int k = 0; k < 16; ++k) { f[k] = __expf(f[k] - m); s += f[k]; }
#pragma unroll
        for (int off = 32; off > 0; off >>= 1) s += __shfl_xor(s, off);
        const float q = 0.25f / s;
#pragma unroll
        for (int k = 0; k < 16; ++k) o[k] += f[k] * q;
    }

    f16x8 o0, o1;
#pragma unroll
    for (int k = 0; k < 8; ++k) { o0[k] = (f16)o[k]; o1[k] = (f16)o[k + 8]; }
    f16x8* qp = (f16x8*)(Pb + ((size_t)b * N_ + row) * N_);
    qp[l * 2] = o0;
    qp[l * 2 + 1] = o1;
}

// Final GEMM: out[b] = Pbar[b] @ xT[b]^T, f32 direct. 256 blocks.
__global__ __launch_bounds__(256, 2) void k_g4b(
    const f16* __restrict__ Pb, const f16* __restrict__ xT,
    float* __restrict__ out)
{
    const int i = blockIdx.x;
    const int b = i & 7;
    const int li = i >> 3;            // 0..31
    const int m0 = (li >> 2) * 128;   // 8 m-tiles
    const int d0 = (li & 3) * 128;    // 4 n-tiles
    single_core_f32<N_, N_, D_, N_>(
        Pb + (size_t)b * NN,
        xT + (size_t)b * ND,
        out + (size_t)b * ND, m0, d0);
}

// Merged decomp: z<8 -> x-batch z (f16 hi + transposed hi); z>=8 -> W head
// z-8 (hi only + transpose). Grid (8,16,12); W part uses y<8 only.
__global__ __launch_bounds__(256) void decomp_xw(
    const float* __restrict__ x, const float* __restrict__ W,
    f16* __restrict__ xfh, f16* __restrict__ xT, f16* __restrict__ wTh)
{
    __shared__ f16 tile[64][65];
    __shared__ float tw[64][65];
    const int t = threadIdx.x;
    const int z = blockIdx.z;
    if (z < 8) {
        const int b = z, n0 = blockIdx.y * 64, d0 = blockIdx.x * 64;
        const float* xb = x + (size_t)b * ND;
#pragma unroll
        for (int p = 0; p < 16; ++p) {
            const int idx = t + p * 256;
            const int r = idx >> 6, c = idx & 63;
            const float v = xb[(size_t)(n0 + r) * D_ + d0 + c];
            const f16 h = (f16)v;
            xfh[(size_t)b * ND + (size_t)(n0 + r) * D_ + d0 + c] = h;
            tile[r][c] = h;
        }
        __syncthreads();
#pragma unroll
        for (int p = 0; p < 16; ++p) {
            const int idx = t + p * 256;
            const int r = idx >> 6, c = idx & 63;
            xT[(size_t)b * ND + (size_t)(d0 + r) * N_ + n0 + c] = tile[c][r];
        }
    } else {
        if (blockIdx.y >= 8) return;
        const int h = z - 8, d0 = blockIdx.y * 64, e0 = blockIdx.x * 64;
        const float* Wh = W + (size_t)h * DD;
#pragma unroll
        for (int p = 0; p < 16; ++p) {
            const int idx = t + p * 256;
            const int r = idx >> 6, c = idx & 63;
            tw[r][c] = Wh[(size_t)(d0 + r) * D_ + e0 + c];
        }
        __syncthreads();
#pragma unroll
        for (int p = 0; p < 16; ++p) {
            const int idx = t + p * 256;
            const int r = idx >> 6, c = idx & 63;
            wTh[(size_t)h * DD + (size_t)(e0 + r) * D_ + d0 + c] = (f16)tw[c][r];
        }
    }
}

extern "C" void kernel_launch(void* const* d_in, const int* in_sizes, int n_in,
                              void* d_out, int out_size, void* d_ws, size_t ws_size,
                              hipStream_t stream) {
    const float* x = (const float*)d_in[0];   // [8,1024,512]
    const float* W = (const float*)d_in[1];   // [4,512,512]
    float* out = (float*)d_out;               // [8,1024,512]

    // workspace layout
    char* ws = (char*)d_ws;
    const size_t MB = 1024 * 1024;
    f16*   xfh = (f16*)(ws + 0 * MB);     // 8 MiB
    f16*   xT  = (f16*)(ws + 8 * MB);     // 8 MiB
    f16*   wTh = (f16*)(ws + 16 * MB);    // 2 MiB
    f16*   Yh  = (f16*)(ws + 20 * MB);    // 32 MiB (full batch, 32 z)
    f16*   S   = (f16*)(ws + 52 * MB);    // 64 MiB (full batch, f16)
    f16*   Pb  = (f16*)(ws + 116 * MB);   // 16 MiB (head-mean P, 8 b)

    decomp_xw<<<dim3(8, 16, 12), 256, 0, stream>>>(x, W, xfh, xT, wTh);

    k_g1<<<dim3(256), 512, 0, stream>>>(xfh, wTh, Yh);
    k_g2<<<dim3(512), 512, 0, stream>>>(Yh, xfh, S);
    softmax_mean<<<dim3(2048), 256, 0, stream>>>(S, Pb);
    k_g4b<<<dim3(256), 256, 0, stream>>>(Pb, xT, out);
}